// Round 14
// baseline (107.431 us; speedup 1.0000x reference)
//
#include <hip/hip_runtime.h>

// WeatherLSTM: B=4096 indep. sequences, T=512 steps, H=10, I=O=1.
// R13 = micro-tuned R6 champion (92.4us). Layout: lane = hidden unit k,
// 16 lanes/elem, 4 elems/wave, 1024 waves = 1/SIMD (B-limited; 2-wave
// variants measured >=1.6x issue/elem tax -> net loss, R3/R10).
// Changes vs R6 (each measured-positive or proven-harmless):
//  1) 4 DS ops (was 6): ds_write_b32 hrow[k] + ds_read_b128 x2 + ds_read_b64,
//     scalar h + 44 scalar FMA dots (same issue as R6's 22 pk, R8 codegen).
//  2) R6's measured-best math: 5 exp2 + 3 rcp; f=rcp(qf) parallel to ig's rcp.
//  3) amdgpu_waves_per_eu(1,1): regalloc headroom (R12-proven harmless).
//  4) no write clamp needed: row stride 16 covers k=0..15 (k>=10 slots never
//     read; inactive lanes' hown==0 exactly).
// Wall model (calibrated R6/R8/R12): trans 4 serial layers ~180-240 cy +
// gather ~80 + dots ~28 + VALU ~60 -> ~400; this kernel trims issue+drain.

#define NLOG2E (-1.4426950408889634f)

typedef float f4v __attribute__((ext_vector_type(4)));
typedef float f2v __attribute__((ext_vector_type(2)));

__global__ __launch_bounds__(256)
__attribute__((amdgpu_waves_per_eu(1, 1)))
void WeatherLSTM_kernel(
    const float* __restrict__ x,     // [B, T, 1]
    const float* __restrict__ W_ih,  // [40, 1]
    const float* __restrict__ W_hh,  // [40, 10]
    const float* __restrict__ b_ih,  // [40]
    const float* __restrict__ b_hh,  // [40]
    const float* __restrict__ W_fc,  // [1, 10]
    const float* __restrict__ b_fc,  // [1]
    float* __restrict__ out,         // [B, 1]
    int T)
{
    __shared__ float hsh[16][16];    // 16 groups x 16 floats (1 KiB)
    const int tid = threadIdx.x;     // 256 = 16 groups of 16 lanes
    const int k   = tid & 15;        // hidden unit; active iff k < 10
    const int grp = tid >> 4;
    const long e  = (long)blockIdx.x * 16 + grp;
    const bool act = (k < 10);
    float* hrow = &hsh[grp][0];

    // Prescaled weights: row scale -L (sigmoid gates i,f,o), -2L (tanh gate g)
    float wh[4][10], wx[4], bb[4];
    #pragma unroll
    for (int t = 0; t < 4; ++t) {
        const float s = (t == 2) ? (2.0f * NLOG2E) : NLOG2E;
        const int g = t * 10 + k;
        wx[t] = act ? W_ih[g] * s : 0.0f;
        bb[t] = act ? (b_ih[g] + b_hh[g]) * s : 0.0f;
        #pragma unroll
        for (int j = 0; j < 10; ++j)
            wh[t][j] = act ? W_hh[g * 10 + j] * s : 0.0f;
    }
    // Inactive lanes (k>=10): args 0 -> p*=1 -> f=.5, ig=0 -> c=0, h=0
    // exactly; they write slots 10..15 which are never read. Safe.

    float h[10];
    #pragma unroll
    for (int j = 0; j < 10; ++j) h[j] = 0.0f;
    float c = 0.0f;

    const float* xe = x + e * (long)T;
    f4v xv = *reinterpret_cast<const f4v*>(xe);
    for (int s0i = 0; s0i < T; s0i += 4) {
        const int snext = (s0i + 4 < T) ? (s0i + 4) : s0i;   // clamped prefetch
        const f4v xnext = *reinterpret_cast<const f4v*>(xe + snext);
        #pragma unroll
        for (int ss = 0; ss < 4; ++ss) {
            const float xt = xv[ss];

            // 4 gate dots, each split A/B -> 8 independent chains, depth 6
            float accA[4], accB[4];
            #pragma unroll
            for (int t = 0; t < 4; ++t) {
                accA[t] = fmaf(xt, wx[t], bb[t]);
                accB[t] = h[5] * wh[t][5];
            }
            #pragma unroll
            for (int j = 0; j < 5; ++j) {
                #pragma unroll
                for (int t = 0; t < 4; ++t)
                    accA[t] = fmaf(h[j], wh[t][j], accA[t]);
            }
            #pragma unroll
            for (int j = 6; j < 10; ++j) {
                #pragma unroll
                for (int t = 0; t < 4; ++t)
                    accB[t] = fmaf(h[j], wh[t][j], accB[t]);
            }
            const float pi = __builtin_amdgcn_exp2f(accA[0] + accB[0]);
            const float pf = __builtin_amdgcn_exp2f(accA[1] + accB[1]);
            const float pg = __builtin_amdgcn_exp2f(accA[2] + accB[2]);
            const float po = __builtin_amdgcn_exp2f(accA[3] + accB[3]);

            // R6 math: f and ig reciprocals run in parallel
            const float qi = 1.0f + pi, qf = 1.0f + pf, qg = 1.0f + pg;
            const float f  = __builtin_amdgcn_rcpf(qf);
            const float ig = (1.0f - pg) * __builtin_amdgcn_rcpf(qi * qg);
            c = fmaf(f, c, ig);

            // h = (1-pc) / ((1+po)(1+pc)),  pc = exp2(-2L*c)
            const float pc = __builtin_amdgcn_exp2f(c * (2.0f * NLOG2E));
            const float qo = 1.0f + po, qc = 1.0f + pc, mc = 1.0f - pc;
            const float hown = mc * __builtin_amdgcn_rcpf(qo * qc);

            // gather: 1 ds_write_b32 + 2 ds_read_b128 + 1 ds_read_b64
            hrow[k] = hown;
            const f4v r0 = *reinterpret_cast<const f4v*>(hrow);
            const f4v r1 = *reinterpret_cast<const f4v*>(hrow + 4);
            const f2v r2 = *reinterpret_cast<const f2v*>(hrow + 8);
            h[0] = r0[0]; h[1] = r0[1]; h[2] = r0[2]; h[3] = r0[3];
            h[4] = r1[0]; h[5] = r1[1]; h[6] = r1[2]; h[7] = r1[3];
            h[8] = r2[0]; h[9] = r2[1];
        }
        xv = xnext;
    }

    if (k == 0) {
        float o = b_fc[0];
        #pragma unroll
        for (int j = 0; j < 10; ++j)
            o = fmaf(h[j], W_fc[j], o);
        out[e] = o;
    }
}

extern "C" void kernel_launch(void* const* d_in, const int* in_sizes, int n_in,
                              void* d_out, int out_size, void* d_ws, size_t ws_size,
                              hipStream_t stream) {
    const float* x    = (const float*)d_in[0];
    const float* W_ih = (const float*)d_in[1];
    const float* W_hh = (const float*)d_in[2];
    const float* b_ih = (const float*)d_in[3];
    const float* b_hh = (const float*)d_in[4];
    const float* W_fc = (const float*)d_in[5];
    const float* b_fc = (const float*)d_in[6];
    float* out = (float*)d_out;

    const int B = out_size;          // 4096
    const int T = in_sizes[0] / B;   // 512

    dim3 grid(B / 16), block(256);   // 16 elems/block, 256 blocks = 1 per CU
    hipLaunchKernelGGL(WeatherLSTM_kernel, grid, block, 0, stream,
                       x, W_ih, W_hh, b_ih, b_hh, W_fc, b_fc, out, T);
}

// Round 15
// 98.865 us; speedup vs baseline: 1.0866x; 1.0866x over previous
//
#include <hip/hip_runtime.h>

// WeatherLSTM: B=4096 indep. sequences, T=512 steps, H=10, I=O=1.
// R14 = R6 champion (92.4us) + on-chain trims via VOP3P op_sel broadcast.
// Layout: lane = hidden unit k, 16 lanes/elem, 4 elems/wave, 1024 waves =
// 1/SIMD (B-limited; 2-wave variants measured >=1.6x issue tax, R3/R10).
// MODEL (recalibrated R13): v_pk_fma_f32 is DUAL-RATE fp32 (157.3 TF spec =
// 2x scalar 78.6) -> pk dots = half the issue of scalar. R6 vs R13 A/B: 433
// vs 503 cy/step confirms.
// Changes vs R6 (all on the serial chain):
//  1) compact h storage: op_sel lo/hi-broadcast of a packed PAIR feeds both
//     pk halves -> no {h,h} duplication; gather = ds_write_b32 + 2x
//     ds_read_b128 + ds_read_b64 (4 DS ops, was 6) and no pair-build mov.
//     (R8's op_sel compile failure was a single-VGPR src0; pairs are legal.)
//  2) x consumed from the prefetched float4 via lo/hi broadcast (no xt2 movs).
// Math identical to R6: prescaled weights (-L sigmoid rows, -2L tanh row);
//   f=rcp(1+pf); ig=(1-pg)*rcp((1+pi)(1+pg)); c=fma(f,c,ig);
//   h=(1-pc)*rcp((1+po)(1+pc)), pc=exp2(-2L*c)  -> 5 exp2 + 3 rcp.

#define NLOG2E (-1.4426950408889634f)

typedef float f2 __attribute__((ext_vector_type(2)));
typedef float f4 __attribute__((ext_vector_type(4)));

__device__ __forceinline__ f2 pk_add(f2 a, f2 b) {
    f2 d;
    asm("v_pk_add_f32 %0, %1, %2" : "=v"(d) : "v"(a), "v"(b));
    return d;
}
// src0 lo-broadcast: both output halves use src0.lo (src1/src2 normal)
__device__ __forceinline__ f2 pk_fma_bl(f2 a, f2 b, f2 c) {
    f2 d;
    asm("v_pk_fma_f32 %0, %1, %2, %3 op_sel:[0,0,0] op_sel_hi:[0,1,1]"
        : "=v"(d) : "v"(a), "v"(b), "v"(c));
    return d;
}
// src0 hi-broadcast: both output halves use src0.hi
__device__ __forceinline__ f2 pk_fma_bh(f2 a, f2 b, f2 c) {
    f2 d;
    asm("v_pk_fma_f32 %0, %1, %2, %3 op_sel:[1,0,0] op_sel_hi:[1,1,1]"
        : "=v"(d) : "v"(a), "v"(b), "v"(c));
    return d;
}
__device__ __forceinline__ f2 pk_mul_bh(f2 a, f2 b) {
    f2 d;
    asm("v_pk_mul_f32 %0, %1, %2 op_sel:[1,0] op_sel_hi:[1,1]"
        : "=v"(d) : "v"(a), "v"(b));
    return d;
}

__global__ __launch_bounds__(256, 1) void WeatherLSTM_kernel(
    const float* __restrict__ x,     // [B, T, 1]
    const float* __restrict__ W_ih,  // [40, 1]
    const float* __restrict__ W_hh,  // [40, 10]
    const float* __restrict__ b_ih,  // [40]
    const float* __restrict__ b_hh,  // [40]
    const float* __restrict__ W_fc,  // [1, 10]
    const float* __restrict__ b_fc,  // [1]
    float* __restrict__ out,         // [B, 1]
    int T)
{
    __shared__ float hsh[16][16];    // 16 groups x 16 floats (1 KiB)
    const int tid = threadIdx.x;     // 256 = 16 groups of 16 lanes
    const int k   = tid & 15;        // hidden unit; active iff k < 10
    const int grp = tid >> 4;
    const long e  = (long)blockIdx.x * 16 + grp;
    const bool act = (k < 10);
    float* hrow = &hsh[grp][0];

    // Packed, prescaled weights: {i,f} and {g,o} pairs; row scale -L for
    // sigmoid gates (i,f,o), -2L for the tanh gate (g).
    const float sI = NLOG2E, sF = NLOG2E, sG = 2.0f * NLOG2E, sO = NLOG2E;
    f2 wIF[10], wGO[10], xwIF, xwGO, bIF, bGO;
    {
        const int gi = 0 * 10 + k, gf = 1 * 10 + k, gg = 2 * 10 + k, go = 3 * 10 + k;
        xwIF = act ? f2{W_ih[gi] * sI, W_ih[gf] * sF} : f2{0.f, 0.f};
        xwGO = act ? f2{W_ih[gg] * sG, W_ih[go] * sO} : f2{0.f, 0.f};
        bIF  = act ? f2{(b_ih[gi] + b_hh[gi]) * sI, (b_ih[gf] + b_hh[gf]) * sF}
                   : f2{0.f, 0.f};
        bGO  = act ? f2{(b_ih[gg] + b_hh[gg]) * sG, (b_ih[go] + b_hh[go]) * sO}
                   : f2{0.f, 0.f};
        #pragma unroll
        for (int j = 0; j < 10; ++j) {
            wIF[j] = act ? f2{W_hh[gi * 10 + j] * sI, W_hh[gf * 10 + j] * sF}
                         : f2{0.f, 0.f};
            wGO[j] = act ? f2{W_hh[gg * 10 + j] * sG, W_hh[go * 10 + j] * sO}
                         : f2{0.f, 0.f};
        }
    }
    // Inactive lanes (k>=10): args 0 -> p*=1 -> f=.5, ig=0 -> c=0, hown=0
    // exactly; they write row slots 10..15 which are never read. Safe.

    // Compact h pairs: hp0={h0,h1} hp1={h2,h3} hp2={h4,h5} hp3={h6,h7} hp4={h8,h9}
    f2 hp0{0.f,0.f}, hp1{0.f,0.f}, hp2{0.f,0.f}, hp3{0.f,0.f}, hp4{0.f,0.f};
    float c = 0.0f;

    // One LSTM step; PKX = pk_fma_bl/bh selects xt = XP.lo / XP.hi.
    #define STEP(XP, PKX)                                                     \
    {                                                                         \
        f2 aIF0 = PKX(XP, xwIF, bIF);                                         \
        f2 aGO0 = PKX(XP, xwGO, bGO);                                         \
        f2 aIF1 = pk_mul_bh(hp2, wIF[5]);                                     \
        f2 aGO1 = pk_mul_bh(hp2, wGO[5]);                                     \
        aIF0 = pk_fma_bl(hp0, wIF[0], aIF0); aGO0 = pk_fma_bl(hp0, wGO[0], aGO0); \
        aIF0 = pk_fma_bh(hp0, wIF[1], aIF0); aGO0 = pk_fma_bh(hp0, wGO[1], aGO0); \
        aIF0 = pk_fma_bl(hp1, wIF[2], aIF0); aGO0 = pk_fma_bl(hp1, wGO[2], aGO0); \
        aIF0 = pk_fma_bh(hp1, wIF[3], aIF0); aGO0 = pk_fma_bh(hp1, wGO[3], aGO0); \
        aIF0 = pk_fma_bl(hp2, wIF[4], aIF0); aGO0 = pk_fma_bl(hp2, wGO[4], aGO0); \
        aIF1 = pk_fma_bl(hp3, wIF[6], aIF1); aGO1 = pk_fma_bl(hp3, wGO[6], aGO1); \
        aIF1 = pk_fma_bh(hp3, wIF[7], aIF1); aGO1 = pk_fma_bh(hp3, wGO[7], aGO1); \
        aIF1 = pk_fma_bl(hp4, wIF[8], aIF1); aGO1 = pk_fma_bl(hp4, wGO[8], aGO1); \
        aIF1 = pk_fma_bh(hp4, wIF[9], aIF1); aGO1 = pk_fma_bh(hp4, wGO[9], aGO1); \
        const f2 aIF = pk_add(aIF0, aIF1);                                    \
        const f2 aGO = pk_add(aGO0, aGO1);                                    \
        const float pi = __builtin_amdgcn_exp2f(aIF[0]);                      \
        const float pf = __builtin_amdgcn_exp2f(aIF[1]);                      \
        const float pg = __builtin_amdgcn_exp2f(aGO[0]);                      \
        const float po = __builtin_amdgcn_exp2f(aGO[1]);                      \
        const float qi = 1.0f + pi, qf = 1.0f + pf, qg = 1.0f + pg;           \
        const float fg = __builtin_amdgcn_rcpf(qf);                           \
        const float ig = (1.0f - pg) * __builtin_amdgcn_rcpf(qi * qg);        \
        c = fmaf(fg, c, ig);                                                  \
        const float pc = __builtin_amdgcn_exp2f(c * (2.0f * NLOG2E));         \
        const float qo = 1.0f + po, qc = 1.0f + pc, mc = 1.0f - pc;           \
        const float hown = mc * __builtin_amdgcn_rcpf(qo * qc);               \
        hrow[k] = hown;                                                       \
        const f4 r0 = *reinterpret_cast<const f4*>(hrow);                     \
        const f4 r1 = *reinterpret_cast<const f4*>(hrow + 4);                 \
        const f2 r2 = *reinterpret_cast<const f2*>(hrow + 8);                 \
        hp0 = f2{r0[0], r0[1]}; hp1 = f2{r0[2], r0[3]};                       \
        hp2 = f2{r1[0], r1[1]}; hp3 = f2{r1[2], r1[3]};                       \
        hp4 = r2;                                                             \
    }

    const float* xe = x + e * (long)T;
    f4 xv = *reinterpret_cast<const f4*>(xe);
    for (int s0i = 0; s0i < T; s0i += 4) {
        const int snext = (s0i + 4 < T) ? (s0i + 4) : s0i;   // clamped prefetch
        const f4 xnext = *reinterpret_cast<const f4*>(xe + snext);
        const f2 xp01 = f2{xv[0], xv[1]};
        const f2 xp23 = f2{xv[2], xv[3]};
        STEP(xp01, pk_fma_bl)
        STEP(xp01, pk_fma_bh)
        STEP(xp23, pk_fma_bl)
        STEP(xp23, pk_fma_bh)
        xv = xnext;
    }
    #undef STEP

    if (k == 0) {
        float o = b_fc[0];
        o = fmaf(hp0[0], W_fc[0], o); o = fmaf(hp0[1], W_fc[1], o);
        o = fmaf(hp1[0], W_fc[2], o); o = fmaf(hp1[1], W_fc[3], o);
        o = fmaf(hp2[0], W_fc[4], o); o = fmaf(hp2[1], W_fc[5], o);
        o = fmaf(hp3[0], W_fc[6], o); o = fmaf(hp3[1], W_fc[7], o);
        o = fmaf(hp4[0], W_fc[8], o); o = fmaf(hp4[1], W_fc[9], o);
        out[e] = o;
    }
}

extern "C" void kernel_launch(void* const* d_in, const int* in_sizes, int n_in,
                              void* d_out, int out_size, void* d_ws, size_t ws_size,
                              hipStream_t stream) {
    const float* x    = (const float*)d_in[0];
    const float* W_ih = (const float*)d_in[1];
    const float* W_hh = (const float*)d_in[2];
    const float* b_ih = (const float*)d_in[3];
    const float* b_hh = (const float*)d_in[4];
    const float* W_fc = (const float*)d_in[5];
    const float* b_fc = (const float*)d_in[6];
    float* out = (float*)d_out;

    const int B = out_size;          // 4096
    const int T = in_sizes[0] / B;   // 512

    dim3 grid(B / 16), block(256);   // 16 elems/block, 256 blocks = 1 per CU
    hipLaunchKernelGGL(WeatherLSTM_kernel, grid, block, 0, stream,
                       x, W_ih, W_hh, b_ih, b_hh, W_fc, b_fc, out, T);
}